// Round 1
// baseline (27255.518 us; speedup 1.0000x reference)
//
#include <hip/hip_runtime.h>
#include <hip/hip_bf16.h>
#include <cstddef>

// Problem constants
#define B_  256
#define T_  256
#define D_  256
#define H_  384
#define G_  1542
#define L_  3
#define CH_ 128
#define K_  10
#define HS_ 64

__device__ __forceinline__ float sigf(float x) { return 1.f / (1.f + expf(-x)); }

// ---------------- init ----------------
__global__ void k_zero(float* __restrict__ p, int n) {
    int i = blockIdx.x * blockDim.x + threadIdx.x;
    if (i < n) p[i] = 0.f;
}

// ---------------- Wc transpose: WcT[k][h][o] = Wc[o][h][k] ----------------
__global__ void k_wct(const float* __restrict__ Wc, float* __restrict__ WcT) {
    int idx = blockIdx.x * 256 + threadIdx.x;      // < K*H*H = 1474560
    int o   = idx % H_;
    int rem = idx / H_;
    int h   = rem % H_;
    int k   = rem / H_;
    WcT[idx] = Wc[(size_t)(o * H_ + h) * K_ + k];
}

// ---------------- per-step GEMM: xo[b,g] ----------------
// xo = [x_t,1]@Wk + bk + [h_{t-1},1]@Wr + br   (inner = 256 + 384 = 640)
__global__ __launch_bounds__(256)
void k_xo(const float* __restrict__ x, const float* __restrict__ Wk,
          const float* __restrict__ bk, const float* __restrict__ Wr,
          const float* __restrict__ br, const float* __restrict__ h_all,
          float* __restrict__ xo, int t)
{
    __shared__ float As[64][34];                    // [inner][b]
    __shared__ __align__(16) float Bs[64][68];      // [inner][g]
    const int g0 = blockIdx.x * 64;
    const int b0 = blockIdx.y * 32;
    const int tid = threadIdx.x;
    const int tg = tid & 15;     // 4 g's each -> 64
    const int tb = tid >> 4;     // 2 b's each -> 32
    const float* hprev = h_all + (size_t)(t - 1) * B_ * H_;

    float acc[2][4] = {};
    for (int c0 = 0; c0 < 640; c0 += 64) {
        // stage A: 64 inner x 32 b
        #pragma unroll
        for (int r = 0; r < 8; ++r) {
            int idx = r * 256 + tid;
            int ii = tid & 63;
            int bb = idx >> 6;
            int ig = c0 + ii;
            float v;
            if (ig < 256) v = x[((size_t)(b0 + bb) * T_ + t) * D_ + ig];
            else          v = (t > 0) ? hprev[(size_t)(b0 + bb) * H_ + (ig - 256)] : 0.f;
            As[ii][bb] = v;
        }
        // stage B: 64 inner x 64 g
        #pragma unroll
        for (int r = 0; r < 16; ++r) {
            int idx = r * 256 + tid;
            int gg = tid & 63;
            int ii = idx >> 6;
            int g = g0 + gg;
            int ig = c0 + ii;
            float v = 0.f;
            if (g < G_) v = (ig < 256) ? Wk[(size_t)ig * G_ + g]
                                       : Wr[(size_t)(ig - 256) * G_ + g];
            Bs[ii][gg] = v;
        }
        __syncthreads();
        #pragma unroll
        for (int i = 0; i < 64; ++i) {
            float a0 = As[i][tb * 2 + 0];
            float a1 = As[i][tb * 2 + 1];
            float4 bv = *(const float4*)&Bs[i][tg * 4];
            acc[0][0] = fmaf(a0, bv.x, acc[0][0]);
            acc[0][1] = fmaf(a0, bv.y, acc[0][1]);
            acc[0][2] = fmaf(a0, bv.z, acc[0][2]);
            acc[0][3] = fmaf(a0, bv.w, acc[0][3]);
            acc[1][0] = fmaf(a1, bv.x, acc[1][0]);
            acc[1][1] = fmaf(a1, bv.y, acc[1][1]);
            acc[1][2] = fmaf(a1, bv.z, acc[1][2]);
            acc[1][3] = fmaf(a1, bv.w, acc[1][3]);
        }
        __syncthreads();
    }
    #pragma unroll
    for (int j = 0; j < 2; ++j) {
        int b = b0 + tb * 2 + j;
        #pragma unroll
        for (int q = 0; q < 4; ++q) {
            int g = g0 + tg * 4 + q;
            if (g < G_) {
                float v = acc[j][q] + bk[g] + br[g]
                        + Wk[(size_t)256 * G_ + g] + Wr[(size_t)384 * G_ + g];
                xo[(size_t)b * G_ + g] = v;
            }
        }
    }
}

// ---------------- gates: c,h update + dis ----------------
__global__ __launch_bounds__(384)
void k_gates(const float* __restrict__ xo, float* __restrict__ c,
             float* __restrict__ h_all, float* __restrict__ dis_all, int t)
{
    const int b = blockIdx.x;
    const int tid = threadIdx.x;                    // 0..383 -> (l,ch)
    const float* row = xo + (size_t)b * G_;

    float z0 = row[0], z1 = row[1], z2 = row[2];
    float z3 = row[3], z4 = row[4], z5 = row[5];
    // cumax l2r over z0..z2
    float m1 = fmaxf(fmaxf(z0, z1), z2);
    float e0 = expf(z0 - m1), e1 = expf(z1 - m1), e2 = expf(z2 - m1);
    float s1 = e0 + e1 + e2;
    float fm0 = e0 / s1, fm1 = (e0 + e1) / s1;      // fm2 = 1
    // cumax r2l over z3..z5 (suffix sums of softmax)
    float m2 = fmaxf(fmaxf(z3, z4), z5);
    float f3 = expf(z3 - m2), f4 = expf(z4 - m2), f5 = expf(z5 - m2);
    float s2 = f3 + f4 + f5;
    float im1 = (f4 + f5) / s2, im2 = f5 / s2;      // im0 = 1

    int l = tid >> 7;                               // /128
    float fm = (l == 0) ? fm0 : (l == 1) ? fm1 : 1.f;
    float im = (l == 0) ? 1.f : (l == 1) ? im1 : im2;

    float fg = sigf(row[6 + tid]);          // rows 0..2
    float ig = sigf(row[6 + 384 + tid]);    // rows 3..5
    float og = sigf(row[6 + 768 + tid]);    // rows 6..8
    float ci = tanhf(row[6 + 1152 + tid]);  // rows 9..11

    float cl = c[(size_t)b * H_ + tid];
    float ov = fm * im;
    float cn = ov * (fg * cl + ig * ci) + (fm - ov) * cl + (im - ov) * ci;
    float hn = og * tanhf(cn);

    c[(size_t)b * H_ + tid] = cn;
    h_all[((size_t)t * B_ + b) * H_ + tid] = hn;
    if (tid == 0) dis_all[t * B_ + b] = 1.f - (fm0 + fm1 + 1.f) * (1.f / 3.f);
}

// ---------------- ld weights: softmax(cumsum(window dis)) ----------------
__global__ void k_ld(const float* __restrict__ dis_all, float* __restrict__ ld_all)
{
    int t = blockIdx.x, b = threadIdx.x;
    float s = 0.f, sk[K_];
    #pragma unroll
    for (int k = 0; k < K_; ++k) {
        int tau = t - (K_ - 1) + k;
        float d = (tau >= 0) ? dis_all[tau * B_ + b] : 0.f;
        s += d; sk[k] = s;
    }
    float m = sk[0];
    #pragma unroll
    for (int k = 1; k < K_; ++k) m = fmaxf(m, sk[k]);
    float sum = 0.f;
    #pragma unroll
    for (int k = 0; k < K_; ++k) { sk[k] = expf(sk[k] - m); sum += sk[k]; }
    float inv = 1.f / sum;
    #pragma unroll
    for (int k = 0; k < K_; ++k)
        ld_all[((size_t)t * B_ + b) * K_ + k] = sk[k] * inv;
}

// ---------------- conv GEMM: out_raw[b,t,o] = sum_{k,h} ld*h_win*WcT ----------------
__global__ __launch_bounds__(256)
void k_conv(const float* __restrict__ h_all, const float* __restrict__ ld_all,
            const float* __restrict__ WcT, float* __restrict__ out_part)
{
    __shared__ __align__(16) float As[32][68];      // [inner][b]
    __shared__ __align__(16) float Bs[32][132];     // [inner][o]
    __shared__ float lds[64][13];
    const int b0 = blockIdx.x * 64;
    const int o0 = blockIdx.y * 128;
    const int t  = blockIdx.z;
    const int tid = threadIdx.x;
    const int to = tid & 31;    // 4 o's each -> 128
    const int tb = tid >> 5;    // 8 b's each -> 64

    for (int idx = tid; idx < 64 * K_; idx += 256) {
        int bb = idx / K_, k = idx % K_;
        lds[bb][k] = ld_all[((size_t)t * B_ + b0 + bb) * K_ + k];
    }
    __syncthreads();

    float acc[8][4] = {};
    for (int cidx = 0; cidx < 120; ++cidx) {        // inner 3840 in chunks of 32
        int k  = cidx / 12;
        int hb = (cidx % 12) * 32;
        int tau = t - (K_ - 1) + k;
        const float* hp = h_all + (size_t)tau * B_ * H_;
        #pragma unroll
        for (int r = 0; r < 8; ++r) {
            int idx = r * 256 + tid;
            int i  = tid & 31;
            int bb = idx >> 5;
            float v = 0.f;
            if (tau >= 0) v = hp[(size_t)(b0 + bb) * H_ + hb + i] * lds[bb][k];
            As[i][bb] = v;
        }
        #pragma unroll
        for (int r = 0; r < 16; ++r) {
            int idx = r * 256 + tid;
            int oo = tid & 127;
            int i  = idx >> 7;
            Bs[i][oo] = WcT[(size_t)(cidx * 32 + i) * H_ + o0 + oo];
        }
        __syncthreads();
        #pragma unroll
        for (int i = 0; i < 32; ++i) {
            float4 a0 = *(const float4*)&As[i][tb * 8];
            float4 a1 = *(const float4*)&As[i][tb * 8 + 4];
            float4 bv = *(const float4*)&Bs[i][to * 4];
            float av[8] = {a0.x, a0.y, a0.z, a0.w, a1.x, a1.y, a1.z, a1.w};
            float bw[4] = {bv.x, bv.y, bv.z, bv.w};
            #pragma unroll
            for (int j = 0; j < 8; ++j)
                #pragma unroll
                for (int q = 0; q < 4; ++q)
                    acc[j][q] = fmaf(av[j], bw[q], acc[j][q]);
        }
        __syncthreads();
    }
    #pragma unroll
    for (int j = 0; j < 8; ++j) {
        int b = b0 + tb * 8 + j;
        float4 v = make_float4(acc[j][0], acc[j][1], acc[j][2], acc[j][3]);
        *(float4*)&out_part[((size_t)b * T_ + t) * H_ + o0 + to * 4] = v;
    }
}

// ---------------- theme + combine: out = h + theme*(conv_raw + bc) ----------------
__global__ __launch_bounds__(256)
void k_theme(const float* __restrict__ h_all, const float* __restrict__ ld_all,
             const float* __restrict__ Ws, const float* __restrict__ bs,
             const float* __restrict__ Wrs, const float* __restrict__ brs,
             const float* __restrict__ bc, float* __restrict__ out_part)
{
    __shared__ float hbar[16][385];
    __shared__ float us[16][65];
    __shared__ float lds[16][13];
    const int b0 = blockIdx.x * 16;
    const int t  = blockIdx.y;
    const int tid = threadIdx.x;

    for (int idx = tid; idx < 16 * K_; idx += 256) {
        int bb = idx / K_, k = idx % K_;
        lds[bb][k] = ld_all[((size_t)t * B_ + b0 + bb) * K_ + k];
    }
    __syncthreads();
    // hbar = mean_k(ld_k * h_win_k)
    for (int idx = tid; idx < 16 * H_; idx += 256) {
        int bb = idx / H_, h = idx % H_;
        float s = 0.f;
        #pragma unroll
        for (int k = 0; k < K_; ++k) {
            int tau = t - (K_ - 1) + k;
            if (tau >= 0)
                s += lds[bb][k] * h_all[((size_t)tau * B_ + b0 + bb) * H_ + h];
        }
        hbar[bb][h] = s * (1.f / K_);
    }
    __syncthreads();
    // u = relu(hbar @ Ws + bs)
    for (int idx = tid; idx < 16 * HS_; idx += 256) {
        int bb = idx / HS_, j = idx % HS_;
        float s = bs[j];
        for (int h = 0; h < H_; ++h) s = fmaf(hbar[bb][h], Ws[h * HS_ + j], s);
        us[bb][j] = fmaxf(s, 0.f);
    }
    __syncthreads();
    // theme = sigmoid(u @ Wrs + brs); combine
    for (int idx = tid; idx < 16 * H_; idx += 256) {
        int bb = idx / H_, o = idx % H_;
        float s = brs[o];
        #pragma unroll
        for (int j = 0; j < HS_; ++j) s = fmaf(us[bb][j], Wrs[j * H_ + o], s);
        float th = sigf(s);
        size_t gi = ((size_t)(b0 + bb) * T_ + t) * H_ + o;
        out_part[gi] = h_all[((size_t)t * B_ + b0 + bb) * H_ + o]
                     + th * (out_part[gi] + bc[o]);
    }
}

// ---------------- last_output gather ----------------
__global__ void k_last(const int* __restrict__ len_i, const float* __restrict__ out_part,
                       float* __restrict__ last)
{
    int b = blockIdx.x, tid = threadIdx.x;
    // lengths declared int64 in the reference; harness may deliver int32 or int64.
    // If int64: word 1 is the hi-word of lengths[0] == 0 (values are 1..256).
    // If int32: word 1 is lengths[1] >= 1. Deterministic per fixed input.
    bool is64 = (len_i[1] == 0);
    long long v = is64 ? ((const long long*)len_i)[b] : (long long)len_i[b];
    int idx = (int)v;
    idx = max(1, min(T_, idx)) - 1;
    last[(size_t)b * H_ + tid] = out_part[((size_t)b * T_ + idx) * H_ + tid];
}

extern "C" void kernel_launch(void* const* d_in, const int* in_sizes, int n_in,
                              void* d_out, int out_size, void* d_ws, size_t ws_size,
                              hipStream_t stream) {
    const float* x   = (const float*)d_in[0];
    const int*   len = (const int*)d_in[1];
    const float* Wk  = (const float*)d_in[2];
    const float* bk  = (const float*)d_in[3];
    const float* Wr  = (const float*)d_in[4];
    const float* br  = (const float*)d_in[5];
    const float* Ws  = (const float*)d_in[6];
    const float* bs  = (const float*)d_in[7];
    const float* Wrs = (const float*)d_in[8];
    const float* brs = (const float*)d_in[9];
    const float* Wc  = (const float*)d_in[10];
    const float* bc  = (const float*)d_in[11];

    float* out      = (float*)d_out;
    float* last     = out;                              // (B,H)
    float* out_part = out + (size_t)B_ * H_;            // (B,T,H)

    // workspace layout (floats); total ~27.9M floats (~111.4 MB)
    float* w     = (float*)d_ws;
    float* c     = w;                                   // B*H
    float* dis   = c     + (size_t)B_ * H_;             // T*B
    float* xo    = dis   + (size_t)T_ * B_;             // B*G
    float* ld    = xo    + (size_t)B_ * G_;             // T*B*K
    float* h_all = ld    + (size_t)T_ * B_ * K_;        // T*B*H
    float* wct   = h_all + (size_t)T_ * B_ * H_;        // K*H*H

    k_zero<<<(B_ * H_ + 255) / 256, 256, 0, stream>>>(c, B_ * H_);
    k_wct<<<(K_ * H_ * H_) / 256, 256, 0, stream>>>(Wc, wct);

    for (int t = 0; t < T_; ++t) {
        k_xo<<<dim3(25, 8), 256, 0, stream>>>(x, Wk, bk, Wr, br, h_all, xo, t);
        k_gates<<<B_, 384, 0, stream>>>(xo, c, h_all, dis, t);
    }

    k_ld<<<T_, B_, 0, stream>>>(dis, ld);
    k_conv<<<dim3(4, 3, T_), 256, 0, stream>>>(h_all, ld, wct, out_part);
    k_theme<<<dim3(16, T_), 256, 0, stream>>>(h_all, ld, Ws, bs, Wrs, brs, bc, out_part);
    k_last<<<B_, H_, 0, stream>>>(len, out_part, last);
}